// Round 1
// baseline (995.968 us; speedup 1.0000x reference)
//
#include <hip/hip_runtime.h>
#include <hip/hip_bf16.h>

#define NN 50000
#define HH 4
#define RR 3
#define EE 524288      // 2^19
#define ESHIFT 19
#define TN (RR*NN)     // 150000
#define NCHUNK ((TN + 1023)/1024)  // 147

typedef __attribute__((ext_vector_type(8))) short short8;
typedef __attribute__((ext_vector_type(4))) float float4v;

// ---------------- conversion kernels ----------------

__global__ void conv_bf16_kernel(const float* __restrict__ in, __hip_bfloat16* __restrict__ out, int n) {
    int i = blockIdx.x * 256 + threadIdx.x;
    if (i < n) out[i] = __float2bfloat16(in[i]);
}

__global__ void relu_conv_kernel(const float* __restrict__ in, __hip_bfloat16* __restrict__ out, int n) {
    int i = blockIdx.x * 256 + threadIdx.x;
    if (i < n) {
        float v = in[i];
        out[i] = __float2bfloat16(v > 0.f ? v : 0.f);
    }
}

// W: [3][128][NC] f32  ->  Wt: [3][NC][128] bf16 (transposed per table)
__global__ void transpose_w_kernel(const float* __restrict__ W, __hip_bfloat16* __restrict__ Wt, int NC) {
    int i = blockIdx.x * 256 + threadIdx.x;
    int per = 128 * NC;
    int t = i / per;
    int rem = i - t * per;
    int k = rem / NC;
    int n = rem - k * NC;
    Wt[t * per + n * 128 + k] = __float2bfloat16(W[i]);
}

// ---------------- CSR build ----------------

__global__ void hist_kernel(const int* __restrict__ dst, int* __restrict__ deg) {
    int i = blockIdx.x * 256 + threadIdx.x;   // < 3E exact
    int r = i >> ESHIFT;
    atomicAdd(&deg[r * NN + dst[i]], 1);
}

__global__ void scan1_kernel(const int* __restrict__ deg, int* __restrict__ part) {
    __shared__ int s[256];
    int t = threadIdx.x;
    int base = blockIdx.x * 1024 + t * 4;
    int sum = 0;
#pragma unroll
    for (int j = 0; j < 4; j++) {
        int idx = base + j;
        sum += (idx < TN) ? deg[idx] : 0;
    }
    s[t] = sum;
    __syncthreads();
    for (int off = 128; off > 0; off >>= 1) {
        if (t < off) s[t] += s[t + off];
        __syncthreads();
    }
    if (t == 0) part[blockIdx.x] = s[0];
}

__global__ void scan2_kernel(int* part) {
    int run = 0;
    for (int i = 0; i < NCHUNK; i++) {
        int v = part[i];
        part[i] = run;
        run += v;
    }
}

__global__ void scan3_kernel(const int* __restrict__ deg, const int* __restrict__ part,
                             int* __restrict__ offs, int* __restrict__ curs) {
    __shared__ int s[256];
    int t = threadIdx.x;
    int base = blockIdx.x * 1024 + t * 4;
    int v[4];
    int tsum = 0;
#pragma unroll
    for (int j = 0; j < 4; j++) {
        int idx = base + j;
        v[j] = (idx < TN) ? deg[idx] : 0;
        tsum += v[j];
    }
    s[t] = tsum;
    __syncthreads();
    for (int off = 1; off < 256; off <<= 1) {
        int x = (t >= off) ? s[t - off] : 0;
        __syncthreads();
        s[t] += x;
        __syncthreads();
    }
    int excl = s[t] - tsum + part[blockIdx.x];
    int run = excl;
#pragma unroll
    for (int j = 0; j < 4; j++) {
        int idx = base + j;
        if (idx < TN) {
            offs[idx] = run;
            curs[idx] = run;
            run += v[j];
        }
    }
}

__global__ void scatter_kernel(const int* __restrict__ src, const int* __restrict__ dst,
                               int* __restrict__ curs, int* __restrict__ esrc) {
    int i = blockIdx.x * 256 + threadIdx.x;   // < 3E exact
    int r = i >> ESHIFT;
    int pos = atomicAdd(&curs[r * NN + dst[i]], 1);
    esrc[pos] = src[i];
}

// ---------------- GEMM: C[M,NC] = A[M,128] @ B[128,NC], B given transposed bf16 [NC,128] ----------------
// block = 256 (4 waves); block tile 64 rows x 64 cols; wave w: rows [w*16, w*16+16), all 64 cols.

__launch_bounds__(256)
__global__ void gemm_kernel(const __hip_bfloat16* __restrict__ A,
                            const __hip_bfloat16* __restrict__ Bt,   // [NC,128]
                            float* __restrict__ C,
                            int M, int NC) {
    __shared__ __hip_bfloat16 Bs[64 * 136];   // 64 cols x 128 k, stride 136 (pad: 2-way LDS aliasing only)
    int tile_m = blockIdx.x * 64;
    int tile_n = blockIdx.y * 64;
    int t = threadIdx.x;

    // stage Bt[tile_n..+64][0..128] -> Bs (row n contiguous in k)
    {
        const uint4* gsrc = (const uint4*)(Bt + (size_t)tile_n * 128);
        for (int e = t; e < 64 * 16; e += 256) {
            int n = e >> 4, c = e & 15;
            uint4 val = gsrc[n * 16 + c];
            *(uint4*)(&Bs[n * 136 + c * 8]) = val;
        }
    }
    __syncthreads();

    int w = t >> 6, lane = t & 63;
    int m16 = lane & 15, quad = lane >> 4;
    int row = tile_m + w * 16 + m16;
    int rowc = row < M ? row : M - 1;

    short8 a[4];
    const short8* ap = (const short8*)(A + (size_t)rowc * 128);
#pragma unroll
    for (int kf = 0; kf < 4; kf++) a[kf] = ap[quad + kf * 4];

    float4v acc[4];
#pragma unroll
    for (int ct = 0; ct < 4; ct++) {
        acc[ct] = (float4v){0.f, 0.f, 0.f, 0.f};
        const short8* bp = (const short8*)(Bs + (ct * 16 + m16) * 136);
#pragma unroll
        for (int kf = 0; kf < 4; kf++) {
            short8 b = bp[quad + kf * 4];
            acc[ct] = __builtin_amdgcn_mfma_f32_16x16x32_bf16(a[kf], b, acc[ct], 0, 0, 0);
        }
    }

#pragma unroll
    for (int ct = 0; ct < 4; ct++) {
        int col = tile_n + ct * 16 + m16;
#pragma unroll
        for (int rg = 0; rg < 4; rg++) {
            int rr = tile_m + w * 16 + quad * 4 + rg;
            if (rr < M) C[(size_t)rr * NC + col] = acc[ct][rg];
        }
    }
}

// ---------------- fused per-node softmax + aggregation ----------------
// One wave per node. V = f32 elems per lane (2 for D=32, 4 for D=64). Row = H*D = 64*V.
// Head = lane>>4 (16-lane groups); single pass: den and acc computed together
// (out = sum(exp(e)*hs) / (sum(exp(e)) + 1e-9), identical to ref since max-subtraction cancels).

template <int V>
__launch_bounds__(256)
__global__ void agg_kernel(const float* __restrict__ hs, const float* __restrict__ hd,
                           const float* __restrict__ a,            // [64*V] for this relation
                           const int* __restrict__ offs, const int* __restrict__ deg,
                           const int* __restrict__ esrc,
                           float* __restrict__ out, int rbase, int accum) {
    const int RD = 64 * V;
    int wid = (blockIdx.x * 256 + threadIdx.x) >> 6;  // node id, < 50000 exact
    int lane = threadIdx.x & 63;
    int eb = lane * V;

    float hdv[V], al[V], acc[V];
#pragma unroll
    for (int j = 0; j < V; j++) {
        hdv[j] = hd[(size_t)wid * RD + eb + j];
        al[j] = a[eb + j];
        acc[j] = 0.f;
    }
    float den = 0.f;
    int e0 = offs[rbase + wid];
    int dg = deg[rbase + wid];
    for (int e = e0; e < e0 + dg; ++e) {
        int u = esrc[e];
        float hv[V];
        float s = 0.f;
#pragma unroll
        for (int j = 0; j < V; j++) {
            hv[j] = hs[(size_t)u * RD + eb + j];
            float m = hv[j] + hdv[j];
            float lr = m > 0.f ? m : 0.2f * m;
            s += lr * al[j];
        }
        s += __shfl_xor(s, 1);
        s += __shfl_xor(s, 2);
        s += __shfl_xor(s, 4);
        s += __shfl_xor(s, 8);
        float ee = __expf(s);
        den += ee;
#pragma unroll
        for (int j = 0; j < V; j++) acc[j] += ee * hv[j];
    }
    float inv = 1.f / (den + 1e-9f);
#pragma unroll
    for (int j = 0; j < V; j++) {
        float res = acc[j] * inv;
        size_t o = (size_t)wid * RD + eb + j;
        if (accum) out[o] += res;
        else out[o] = res;
    }
}

// ---------------- launch ----------------

extern "C" void kernel_launch(void* const* d_in, const int* in_sizes, int n_in,
                              void* d_out, int out_size, void* d_ws, size_t ws_size,
                              hipStream_t stream) {
    const float* x   = (const float*)d_in[0];
    const int*   src = (const int*)d_in[1];
    const int*   dst = (const int*)d_in[2];
    const float* W1s = (const float*)d_in[3];
    const float* W1d = (const float*)d_in[4];
    const float* a1  = (const float*)d_in[5];
    const float* W2s = (const float*)d_in[6];
    const float* W2d = (const float*)d_in[7];
    const float* a2  = (const float*)d_in[8];

    char* ws = (char*)d_ws;
    size_t off = 0;
    auto alloc = [&](size_t bytes) -> void* {
        void* p = ws + off;
        off += (bytes + 255) & ~(size_t)255;
        return p;
    };
    __hip_bfloat16* xb   = (__hip_bfloat16*)alloc((size_t)NN * 128 * 2);
    __hip_bfloat16* hb   = (__hip_bfloat16*)alloc((size_t)NN * 128 * 2);
    float*          hs   = (float*)alloc((size_t)NN * 256 * 4);
    float*          hd   = (float*)alloc((size_t)NN * 256 * 4);
    __hip_bfloat16* W1ts = (__hip_bfloat16*)alloc((size_t)RR * 128 * 128 * 2);
    __hip_bfloat16* W1td = (__hip_bfloat16*)alloc((size_t)RR * 128 * 128 * 2);
    __hip_bfloat16* W2ts = (__hip_bfloat16*)alloc((size_t)RR * 128 * 256 * 2);
    __hip_bfloat16* W2td = (__hip_bfloat16*)alloc((size_t)RR * 128 * 256 * 2);
    int* deg  = (int*)alloc((size_t)TN * 4);
    int* offs = (int*)alloc((size_t)TN * 4);
    int* curs = (int*)alloc((size_t)TN * 4);
    int* esrc = (int*)alloc((size_t)RR * EE * 4);
    int* part = (int*)alloc(4096);

    float* h1   = (float*)d_out;   // layer-1 accumulator aliases d_out (first N*128 floats); dead before agg2 writes
    float* outp = (float*)d_out;

    // conversions
    conv_bf16_kernel<<<25000, 256, 0, stream>>>(x, xb, NN * 128);
    transpose_w_kernel<<<192, 256, 0, stream>>>(W1s, W1ts, 128);
    transpose_w_kernel<<<192, 256, 0, stream>>>(W1d, W1td, 128);
    transpose_w_kernel<<<384, 256, 0, stream>>>(W2s, W2ts, 256);
    transpose_w_kernel<<<384, 256, 0, stream>>>(W2d, W2td, 256);

    // CSR build (shared by both layers)
    hipMemsetAsync(deg, 0, (size_t)TN * 4, stream);
    hist_kernel<<<(RR * EE) / 256, 256, 0, stream>>>(dst, deg);
    scan1_kernel<<<NCHUNK, 256, 0, stream>>>(deg, part);
    scan2_kernel<<<1, 1, 0, stream>>>(part);
    scan3_kernel<<<NCHUNK, 256, 0, stream>>>(deg, part, offs, curs);
    scatter_kernel<<<(RR * EE) / 256, 256, 0, stream>>>(src, dst, curs, esrc);

    dim3 g1(782, 2), g2(782, 4);
    // Layer 1
    for (int r = 0; r < RR; r++) {
        gemm_kernel<<<g1, 256, 0, stream>>>(xb, W1ts + (size_t)r * 128 * 128, hs, NN, 128);
        gemm_kernel<<<g1, 256, 0, stream>>>(xb, W1td + (size_t)r * 128 * 128, hd, NN, 128);
        agg_kernel<2><<<12500, 256, 0, stream>>>(hs, hd, a1 + (size_t)r * 128, offs, deg, esrc,
                                                 h1, r * NN, r > 0);
    }
    relu_conv_kernel<<<25000, 256, 0, stream>>>(h1, hb, NN * 128);
    // Layer 2
    for (int r = 0; r < RR; r++) {
        gemm_kernel<<<g2, 256, 0, stream>>>(hb, W2ts + (size_t)r * 128 * 256, hs, NN, 256);
        gemm_kernel<<<g2, 256, 0, stream>>>(hb, W2td + (size_t)r * 128 * 256, hd, NN, 256);
        agg_kernel<4><<<12500, 256, 0, stream>>>(hs, hd, a2 + (size_t)r * 256, offs, deg, esrc,
                                                 outp, r * NN, r > 0);
    }
}

// Round 2
// 815.469 us; speedup vs baseline: 1.2213x; 1.2213x over previous
//
#include <hip/hip_runtime.h>
#include <hip/hip_bf16.h>

#define NN 50000
#define HH 4
#define RR 3
#define EE 524288      // 2^19
#define ESHIFT 19
#define TN (RR*NN)     // 150000
#define NCHUNK ((TN + 1023)/1024)  // 147

typedef __attribute__((ext_vector_type(8))) short short8;
typedef __attribute__((ext_vector_type(4))) float float4v;

// ---------------- conversion kernels ----------------

__global__ void conv_bf16_kernel(const float* __restrict__ in, __hip_bfloat16* __restrict__ out, int n) {
    int i = blockIdx.x * 256 + threadIdx.x;
    if (i < n) out[i] = __float2bfloat16(in[i]);
}

__global__ void relu_conv_kernel(const float* __restrict__ in, __hip_bfloat16* __restrict__ out, int n) {
    int i = blockIdx.x * 256 + threadIdx.x;
    if (i < n) {
        float v = in[i];
        out[i] = __float2bfloat16(v > 0.f ? v : 0.f);
    }
}

// W: [3][128][NC] f32 -> T: [3*2*NC rows][128] bf16; row (r*2*NC + colOff + n), col k.
__global__ void transpose_w_kernel(const float* __restrict__ W, __hip_bfloat16* __restrict__ T,
                                   int NC, int colOff) {
    int i = blockIdx.x * 256 + threadIdx.x;   // exact: 3*128*NC
    int per = 128 * NC;
    int r = i / per;
    int rem = i - r * per;
    int k = rem / NC;
    int n = rem - k * NC;
    T[(size_t)(r * 2 * NC + colOff + n) * 128 + k] = __float2bfloat16(W[i]);
}

// ---------------- CSR build ----------------

__global__ void hist_kernel(const int* __restrict__ dst, int* __restrict__ deg) {
    int i = blockIdx.x * 256 + threadIdx.x;   // < 3E exact
    int r = i >> ESHIFT;
    atomicAdd(&deg[r * NN + dst[i]], 1);
}

__global__ void scan1_kernel(const int* __restrict__ deg, int* __restrict__ part) {
    __shared__ int s[256];
    int t = threadIdx.x;
    int base = blockIdx.x * 1024 + t * 4;
    int sum = 0;
#pragma unroll
    for (int j = 0; j < 4; j++) {
        int idx = base + j;
        sum += (idx < TN) ? deg[idx] : 0;
    }
    s[t] = sum;
    __syncthreads();
    for (int off = 128; off > 0; off >>= 1) {
        if (t < off) s[t] += s[t + off];
        __syncthreads();
    }
    if (t == 0) part[blockIdx.x] = s[0];
}

__global__ void scan2_kernel(int* part) {
    int run = 0;
    for (int i = 0; i < NCHUNK; i++) {
        int v = part[i];
        part[i] = run;
        run += v;
    }
}

__global__ void scan3_kernel(const int* __restrict__ deg, const int* __restrict__ part,
                             int* __restrict__ offs, int* __restrict__ curs) {
    __shared__ int s[256];
    int t = threadIdx.x;
    int base = blockIdx.x * 1024 + t * 4;
    int v[4];
    int tsum = 0;
#pragma unroll
    for (int j = 0; j < 4; j++) {
        int idx = base + j;
        v[j] = (idx < TN) ? deg[idx] : 0;
        tsum += v[j];
    }
    s[t] = tsum;
    __syncthreads();
    for (int off = 1; off < 256; off <<= 1) {
        int x = (t >= off) ? s[t - off] : 0;
        __syncthreads();
        s[t] += x;
        __syncthreads();
    }
    int excl = s[t] - tsum + part[blockIdx.x];
    int run = excl;
#pragma unroll
    for (int j = 0; j < 4; j++) {
        int idx = base + j;
        if (idx < TN) {
            offs[idx] = run;
            curs[idx] = run;
            run += v[j];
        }
    }
}

__global__ void scatter_kernel(const int* __restrict__ src, const int* __restrict__ dst,
                               int* __restrict__ curs, int* __restrict__ esrc) {
    int i = blockIdx.x * 256 + threadIdx.x;   // < 3E exact
    int r = i >> ESHIFT;
    int pos = atomicAdd(&curs[r * NN + dst[i]], 1);
    esrc[pos] = src[i];
}

// ---------------- GEMM: C[M,NCtot](bf16) = A[M,128](bf16) @ T[NCtot,128]^T ----------------
// block=256 (4 waves); tile 64 rows x 64 cols; wave w: rows [w*16,+16), all 64 cols.

__launch_bounds__(256)
__global__ void gemm_kernel(const __hip_bfloat16* __restrict__ A,
                            const __hip_bfloat16* __restrict__ Bt,   // [NCtot,128]
                            __hip_bfloat16* __restrict__ C,
                            int M, int NCtot) {
    __shared__ __hip_bfloat16 Bs[64 * 136];
    int tile_m = blockIdx.x * 64;
    int tile_n = blockIdx.y * 64;
    int t = threadIdx.x;

    {
        const uint4* gsrc = (const uint4*)(Bt + (size_t)tile_n * 128);
        for (int e = t; e < 64 * 16; e += 256) {
            int n = e >> 4, c = e & 15;
            uint4 val = gsrc[n * 16 + c];
            *(uint4*)(&Bs[n * 136 + c * 8]) = val;
        }
    }
    __syncthreads();

    int w = t >> 6, lane = t & 63;
    int m16 = lane & 15, quad = lane >> 4;
    int row = tile_m + w * 16 + m16;
    int rowc = row < M ? row : M - 1;

    short8 a[4];
    const short8* ap = (const short8*)(A + (size_t)rowc * 128);
#pragma unroll
    for (int kf = 0; kf < 4; kf++) a[kf] = ap[quad + kf * 4];

    float4v acc[4];
#pragma unroll
    for (int ct = 0; ct < 4; ct++) {
        acc[ct] = (float4v){0.f, 0.f, 0.f, 0.f};
        const short8* bp = (const short8*)(Bs + (ct * 16 + m16) * 136);
#pragma unroll
        for (int kf = 0; kf < 4; kf++) {
            short8 b = bp[quad + kf * 4];
            acc[ct] = __builtin_amdgcn_mfma_f32_16x16x32_bf16(a[kf], b, acc[ct], 0, 0, 0);
        }
    }

#pragma unroll
    for (int ct = 0; ct < 4; ct++) {
        int col = tile_n + ct * 16 + m16;
#pragma unroll
        for (int rg = 0; rg < 4; rg++) {
            int rr = tile_m + w * 16 + quad * 4 + rg;
            if (rr < M) C[(size_t)rr * NCtot + col] = __float2bfloat16(acc[ct][rg]);
        }
    }
}

// ---------------- fused per-node softmax + aggregation, all relations in one pass ----------------
// One wave per node. V = elems/lane (2: D=32, 4: D=64). NC = 64*V per half (hs|hd).
// C layout: [N, NCtot] bf16, NCtot = 3*2*NC; relation r: hs at col r*2*NC, hd at +NC.
// out[node] = sum_r ( sum_e exp(e)*hs[src] / (sum_e exp(e) + 1e-9) )   (max-shift cancels; f32 exp safe)

template <int V>
__launch_bounds__(256)
__global__ void agg_kernel(const ushort* __restrict__ C, int NCtot,
                           const float* __restrict__ a,            // [R][64*V]
                           const int* __restrict__ offs, const int* __restrict__ deg,
                           const int* __restrict__ esrc,
                           float* __restrict__ out) {
    const int NC = 64 * V;
    int wid = (blockIdx.x * 256 + threadIdx.x) >> 6;  // node id, < 50000 exact
    int lane = threadIdx.x & 63;
    int eb = lane * V;

    float total[V];
#pragma unroll
    for (int j = 0; j < V; j++) total[j] = 0.f;

#pragma unroll 1
    for (int r = 0; r < RR; r++) {
        int colbase = r * 2 * NC;
        float hdv[V], al[V], acc[V];
        // hd gather (one row per node)
        {
            const ushort* p = C + (size_t)wid * NCtot + colbase + NC + eb;
            if (V == 2) {
                uint pk = *(const uint*)p;
                hdv[0] = __uint_as_float((pk & 0xffffu) << 16);
                hdv[1] = __uint_as_float(pk & 0xffff0000u);
            } else {
                uint2 pk = *(const uint2*)p;
                hdv[0] = __uint_as_float((pk.x & 0xffffu) << 16);
                hdv[1] = __uint_as_float(pk.x & 0xffff0000u);
                hdv[2] = __uint_as_float((pk.y & 0xffffu) << 16);
                hdv[3] = __uint_as_float(pk.y & 0xffff0000u);
            }
        }
#pragma unroll
        for (int j = 0; j < V; j++) {
            al[j] = a[r * NC + eb + j];
            acc[j] = 0.f;
        }
        float den = 0.f;
        int e0 = offs[r * NN + wid];
        int dg = deg[r * NN + wid];
        for (int e = e0; e < e0 + dg; ++e) {
            int u = esrc[e];
            const ushort* p = C + (size_t)u * NCtot + colbase + eb;
            float hv[V];
            if (V == 2) {
                uint pk = *(const uint*)p;
                hv[0] = __uint_as_float((pk & 0xffffu) << 16);
                hv[1] = __uint_as_float(pk & 0xffff0000u);
            } else {
                uint2 pk = *(const uint2*)p;
                hv[0] = __uint_as_float((pk.x & 0xffffu) << 16);
                hv[1] = __uint_as_float(pk.x & 0xffff0000u);
                hv[2] = __uint_as_float((pk.y & 0xffffu) << 16);
                hv[3] = __uint_as_float(pk.y & 0xffff0000u);
            }
            float s = 0.f;
#pragma unroll
            for (int j = 0; j < V; j++) {
                float m = hv[j] + hdv[j];
                float lr = m > 0.f ? m : 0.2f * m;
                s += lr * al[j];
            }
            s += __shfl_xor(s, 1);
            s += __shfl_xor(s, 2);
            s += __shfl_xor(s, 4);
            s += __shfl_xor(s, 8);
            float ee = __expf(s);
            den += ee;
#pragma unroll
            for (int j = 0; j < V; j++) acc[j] += ee * hv[j];
        }
        float inv = 1.f / (den + 1e-9f);
#pragma unroll
        for (int j = 0; j < V; j++) total[j] += acc[j] * inv;
    }

#pragma unroll
    for (int j = 0; j < V; j++) out[(size_t)wid * NC + eb + j] = total[j];
}

// ---------------- launch ----------------

extern "C" void kernel_launch(void* const* d_in, const int* in_sizes, int n_in,
                              void* d_out, int out_size, void* d_ws, size_t ws_size,
                              hipStream_t stream) {
    const float* x   = (const float*)d_in[0];
    const int*   src = (const int*)d_in[1];
    const int*   dst = (const int*)d_in[2];
    const float* W1s = (const float*)d_in[3];
    const float* W1d = (const float*)d_in[4];
    const float* a1  = (const float*)d_in[5];
    const float* W2s = (const float*)d_in[6];
    const float* W2d = (const float*)d_in[7];
    const float* a2  = (const float*)d_in[8];

    char* ws = (char*)d_ws;
    size_t off = 0;
    auto alloc = [&](size_t bytes) -> void* {
        void* p = ws + off;
        off += (bytes + 255) & ~(size_t)255;
        return p;
    };
    __hip_bfloat16* xb = (__hip_bfloat16*)alloc((size_t)NN * 128 * 2);
    __hip_bfloat16* hb = (__hip_bfloat16*)alloc((size_t)NN * 128 * 2);
    __hip_bfloat16* Cb = (__hip_bfloat16*)alloc((size_t)NN * 1536 * 2);  // shared: layer1 uses [N,768], layer2 [N,1536]
    __hip_bfloat16* T1 = (__hip_bfloat16*)alloc((size_t)768 * 128 * 2);
    __hip_bfloat16* T2 = (__hip_bfloat16*)alloc((size_t)1536 * 128 * 2);
    int* deg  = (int*)alloc((size_t)TN * 4);
    int* offs = (int*)alloc((size_t)TN * 4);
    int* curs = (int*)alloc((size_t)TN * 4);
    int* esrc = (int*)alloc((size_t)RR * EE * 4);
    int* part = (int*)alloc(4096);

    float* h1   = (float*)d_out;   // layer-1 output [N,128] f32 aliases d_out; dead before layer-2 agg writes
    float* outp = (float*)d_out;

    // conversions / weight packing
    conv_bf16_kernel<<<25000, 256, 0, stream>>>(x, xb, NN * 128);
    transpose_w_kernel<<<192, 256, 0, stream>>>(W1s, T1, 128, 0);
    transpose_w_kernel<<<192, 256, 0, stream>>>(W1d, T1, 128, 128);
    transpose_w_kernel<<<384, 256, 0, stream>>>(W2s, T2, 256, 0);
    transpose_w_kernel<<<384, 256, 0, stream>>>(W2d, T2, 256, 256);

    // CSR build (shared by both layers)
    hipMemsetAsync(deg, 0, (size_t)TN * 4, stream);
    hist_kernel<<<(RR * EE) / 256, 256, 0, stream>>>(dst, deg);
    scan1_kernel<<<NCHUNK, 256, 0, stream>>>(deg, part);
    scan2_kernel<<<1, 1, 0, stream>>>(part);
    scan3_kernel<<<NCHUNK, 256, 0, stream>>>(deg, part, offs, curs);
    scatter_kernel<<<(RR * EE) / 256, 256, 0, stream>>>(src, dst, curs, esrc);

    // Layer 1: one GEMM [N,128]x[128,768] -> bf16, one agg over 3 relations
    gemm_kernel<<<dim3(782, 12), 256, 0, stream>>>(xb, T1, Cb, NN, 768);
    agg_kernel<2><<<12500, 256, 0, stream>>>((const ushort*)Cb, 768, a1, offs, deg, esrc, h1);
    relu_conv_kernel<<<25000, 256, 0, stream>>>(h1, hb, NN * 128);

    // Layer 2: one GEMM [N,128]x[128,1536] -> bf16, one agg over 3 relations
    gemm_kernel<<<dim3(782, 24), 256, 0, stream>>>(hb, T2, Cb, NN, 1536);
    agg_kernel<4><<<12500, 256, 0, stream>>>((const ushort*)Cb, 1536, a2, offs, deg, esrc, outp);
}

// Round 3
// 651.907 us; speedup vs baseline: 1.5278x; 1.2509x over previous
//
#include <hip/hip_runtime.h>
#include <hip/hip_bf16.h>

#define NN 50000
#define HH 4
#define RR 3
#define EE 524288      // 2^19
#define ESHIFT 19
#define TN (RR*NN)     // 150000
#define NCHUNK ((TN + 1023)/1024)  // 147

typedef __attribute__((ext_vector_type(8))) short short8;
typedef __attribute__((ext_vector_type(4))) float float4v;

// ---------------- conversion kernels ----------------

__global__ void conv_bf16_kernel(const float* __restrict__ in, __hip_bfloat16* __restrict__ out, int n) {
    int i = blockIdx.x * 256 + threadIdx.x;
    if (i < n) out[i] = __float2bfloat16(in[i]);
}

// W: [3][128][NC] f32 -> T: [3*2*NC rows][128] bf16; row (r*2*NC + colOff + n), col k.
__global__ void transpose_w_kernel(const float* __restrict__ W, __hip_bfloat16* __restrict__ T,
                                   int NC, int colOff) {
    int i = blockIdx.x * 256 + threadIdx.x;   // exact: 3*128*NC
    int per = 128 * NC;
    int r = i / per;
    int rem = i - r * per;
    int k = rem / NC;
    int n = rem - k * NC;
    T[(size_t)(r * 2 * NC + colOff + n) * 128 + k] = __float2bfloat16(W[i]);
}

// ---------------- CSR build ----------------

__global__ void hist_kernel(const int* __restrict__ dst, int* __restrict__ deg) {
    int i = blockIdx.x * 256 + threadIdx.x;   // < 3E exact
    int r = i >> ESHIFT;
    atomicAdd(&deg[r * NN + dst[i]], 1);
}

__global__ void scan1_kernel(const int* __restrict__ deg, int* __restrict__ part) {
    __shared__ int s[256];
    int t = threadIdx.x;
    int base = blockIdx.x * 1024 + t * 4;
    int sum = 0;
#pragma unroll
    for (int j = 0; j < 4; j++) {
        int idx = base + j;
        sum += (idx < TN) ? deg[idx] : 0;
    }
    s[t] = sum;
    __syncthreads();
    for (int off = 128; off > 0; off >>= 1) {
        if (t < off) s[t] += s[t + off];
        __syncthreads();
    }
    if (t == 0) part[blockIdx.x] = s[0];
}

__global__ void scan2_kernel(int* part) {
    int run = 0;
    for (int i = 0; i < NCHUNK; i++) {
        int v = part[i];
        part[i] = run;
        run += v;
    }
}

__global__ void scan3_kernel(const int* __restrict__ deg, const int* __restrict__ part,
                             int* __restrict__ offs, int* __restrict__ curs) {
    __shared__ int s[256];
    int t = threadIdx.x;
    int base = blockIdx.x * 1024 + t * 4;
    int v[4];
    int tsum = 0;
#pragma unroll
    for (int j = 0; j < 4; j++) {
        int idx = base + j;
        v[j] = (idx < TN) ? deg[idx] : 0;
        tsum += v[j];
    }
    s[t] = tsum;
    __syncthreads();
    for (int off = 1; off < 256; off <<= 1) {
        int x = (t >= off) ? s[t - off] : 0;
        __syncthreads();
        s[t] += x;
        __syncthreads();
    }
    int excl = s[t] - tsum + part[blockIdx.x];
    int run = excl;
#pragma unroll
    for (int j = 0; j < 4; j++) {
        int idx = base + j;
        if (idx < TN) {
            offs[idx] = run;
            curs[idx] = run;
            run += v[j];
        }
    }
}

__global__ void scatter_kernel(const int* __restrict__ src, const int* __restrict__ dst,
                               int* __restrict__ curs, int* __restrict__ esrc) {
    int i = blockIdx.x * 256 + threadIdx.x;   // < 3E exact
    int r = i >> ESHIFT;
    int pos = atomicAdd(&curs[r * NN + dst[i]], 1);
    esrc[pos] = src[i];
}

// ---------------- GEMM ----------------
// C tables layout: 6 tables [M, NCsub] bf16, table id = global_col >> nshift
// (order: r0_src, r0_dst, r1_src, r1_dst, r2_src, r2_dst).
// block=256 (4 waves); tile 64 rows x 64 cols.

__launch_bounds__(256)
__global__ void gemm_kernel(const __hip_bfloat16* __restrict__ A,
                            const __hip_bfloat16* __restrict__ Bt,   // [NCtot,128]
                            __hip_bfloat16* __restrict__ C,
                            int M, int nshift) {
    __shared__ __hip_bfloat16 Bs[64 * 136];
    int tile_m = blockIdx.x * 64;
    int tile_n = blockIdx.y * 64;
    int t = threadIdx.x;

    {
        const uint4* gsrc = (const uint4*)(Bt + (size_t)tile_n * 128);
        for (int e = t; e < 64 * 16; e += 256) {
            int n = e >> 4, c = e & 15;
            uint4 val = gsrc[n * 16 + c];
            *(uint4*)(&Bs[n * 136 + c * 8]) = val;
        }
    }
    __syncthreads();

    int w = t >> 6, lane = t & 63;
    int m16 = lane & 15, quad = lane >> 4;
    int row = tile_m + w * 16 + m16;
    int rowc = row < M ? row : M - 1;

    short8 a[4];
    const short8* ap = (const short8*)(A + (size_t)rowc * 128);
#pragma unroll
    for (int kf = 0; kf < 4; kf++) a[kf] = ap[quad + kf * 4];

    float4v acc[4];
#pragma unroll
    for (int ct = 0; ct < 4; ct++) {
        acc[ct] = (float4v){0.f, 0.f, 0.f, 0.f};
        const short8* bp = (const short8*)(Bs + (ct * 16 + m16) * 136);
#pragma unroll
        for (int kf = 0; kf < 4; kf++) {
            short8 b = bp[quad + kf * 4];
            acc[ct] = __builtin_amdgcn_mfma_f32_16x16x32_bf16(a[kf], b, acc[ct], 0, 0, 0);
        }
    }

    int cmask = (1 << nshift) - 1;
#pragma unroll
    for (int ct = 0; ct < 4; ct++) {
        int col = tile_n + ct * 16 + m16;
        int tbl = col >> nshift;
        int cc = col & cmask;
        size_t base = ((size_t)tbl * M) << nshift;
#pragma unroll
        for (int rg = 0; rg < 4; rg++) {
            int rr = tile_m + w * 16 + quad * 4 + rg;
            if (rr < M) C[base + (((size_t)rr) << nshift) + cc] = __float2bfloat16(acc[ct][rg]);
        }
    }
}

// ---------------- fused per-node softmax + aggregation ----------------
// One wave per node. V = elems/lane (2: D=32, 4: D=64). NC = 64*V.
// Tables: C + (2r)*N*NC = hs_r, C + (2r+1)*N*NC = hd_r  (each [N,NC] bf16, compact).
// Edge loop unrolled x4: independent gather/swizzle/exp chains hide latency.

template <int V>
__device__ inline void ldrow(const ushort* __restrict__ p, float* hv) {
    if constexpr (V == 2) {
        uint pk = *(const uint*)p;
        hv[0] = __uint_as_float((pk & 0xffffu) << 16);
        hv[1] = __uint_as_float(pk & 0xffff0000u);
    } else {
        uint2 pk = *(const uint2*)p;
        hv[0] = __uint_as_float((pk.x & 0xffffu) << 16);
        hv[1] = __uint_as_float(pk.x & 0xffff0000u);
        hv[2] = __uint_as_float((pk.y & 0xffffu) << 16);
        hv[3] = __uint_as_float(pk.y & 0xffff0000u);
    }
}

template <int V>
__device__ inline float edot(const float* hv, const float* hdv, const float* al) {
    float s = 0.f;
#pragma unroll
    for (int j = 0; j < V; j++) {
        float m = hv[j] + hdv[j];
        float lr = m > 0.f ? m : 0.2f * m;
        s += lr * al[j];
    }
    return s;
}

__device__ inline float hred(float s) {
    s += __shfl_xor(s, 1);
    s += __shfl_xor(s, 2);
    s += __shfl_xor(s, 4);
    s += __shfl_xor(s, 8);
    return s;
}

template <int V, bool L1>
__launch_bounds__(256)
__global__ void agg_kernel(const ushort* __restrict__ C,
                           const float* __restrict__ a,            // [R][64*V]
                           const int* __restrict__ offs, const int* __restrict__ deg,
                           const int* __restrict__ esrc,
                           float* __restrict__ outf, __hip_bfloat16* __restrict__ outb) {
    const int NC = 64 * V;
    int wid = (blockIdx.x * 256 + threadIdx.x) >> 6;  // node id, < 50000 exact
    int lane = threadIdx.x & 63;
    int eb = lane * V;

    float total[V];
#pragma unroll
    for (int j = 0; j < V; j++) total[j] = 0.f;

#pragma unroll 1
    for (int r = 0; r < RR; r++) {
        const ushort* hsb = C + ((size_t)(2 * r) * NN) * NC + eb;
        const ushort* hdb = C + ((size_t)(2 * r + 1) * NN) * NC + eb;
        float hdv[V], al[V], acc[V];
        ldrow<V>(hdb + (size_t)wid * NC, hdv);
#pragma unroll
        for (int j = 0; j < V; j++) {
            al[j] = a[r * NC + eb + j];
            acc[j] = 0.f;
        }
        float den = 0.f;
        int e0 = offs[r * NN + wid];
        int eend = e0 + deg[r * NN + wid];
        int e = e0;
        for (; e + 4 <= eend; e += 4) {
            int u0 = esrc[e], u1 = esrc[e + 1], u2 = esrc[e + 2], u3 = esrc[e + 3];
            float hv0[V], hv1[V], hv2[V], hv3[V];
            ldrow<V>(hsb + (size_t)u0 * NC, hv0);
            ldrow<V>(hsb + (size_t)u1 * NC, hv1);
            ldrow<V>(hsb + (size_t)u2 * NC, hv2);
            ldrow<V>(hsb + (size_t)u3 * NC, hv3);
            float s0 = edot<V>(hv0, hdv, al);
            float s1 = edot<V>(hv1, hdv, al);
            float s2 = edot<V>(hv2, hdv, al);
            float s3 = edot<V>(hv3, hdv, al);
            s0 = hred(s0); s1 = hred(s1); s2 = hred(s2); s3 = hred(s3);
            float p0 = __expf(s0), p1 = __expf(s1), p2 = __expf(s2), p3 = __expf(s3);
            den += (p0 + p1) + (p2 + p3);
#pragma unroll
            for (int j = 0; j < V; j++)
                acc[j] += (p0 * hv0[j] + p1 * hv1[j]) + (p2 * hv2[j] + p3 * hv3[j]);
        }
        for (; e < eend; ++e) {
            int u = esrc[e];
            float hv[V];
            ldrow<V>(hsb + (size_t)u * NC, hv);
            float s = hred(edot<V>(hv, hdv, al));
            float p = __expf(s);
            den += p;
#pragma unroll
            for (int j = 0; j < V; j++) acc[j] += p * hv[j];
        }
        float inv = 1.f / (den + 1e-9f);
#pragma unroll
        for (int j = 0; j < V; j++) total[j] += acc[j] * inv;
    }

    if constexpr (L1) {
#pragma unroll
        for (int j = 0; j < V; j++) {
            float v = total[j];
            outb[(size_t)wid * NC + eb + j] = __float2bfloat16(v > 0.f ? v : 0.f);
        }
    } else {
#pragma unroll
        for (int j = 0; j < V; j++) outf[(size_t)wid * NC + eb + j] = total[j];
    }
}

// ---------------- launch ----------------

extern "C" void kernel_launch(void* const* d_in, const int* in_sizes, int n_in,
                              void* d_out, int out_size, void* d_ws, size_t ws_size,
                              hipStream_t stream) {
    const float* x   = (const float*)d_in[0];
    const int*   src = (const int*)d_in[1];
    const int*   dst = (const int*)d_in[2];
    const float* W1s = (const float*)d_in[3];
    const float* W1d = (const float*)d_in[4];
    const float* a1  = (const float*)d_in[5];
    const float* W2s = (const float*)d_in[6];
    const float* W2d = (const float*)d_in[7];
    const float* a2  = (const float*)d_in[8];

    char* ws = (char*)d_ws;
    size_t off = 0;
    auto alloc = [&](size_t bytes) -> void* {
        void* p = ws + off;
        off += (bytes + 255) & ~(size_t)255;
        return p;
    };
    __hip_bfloat16* xb = (__hip_bfloat16*)alloc((size_t)NN * 128 * 2);
    __hip_bfloat16* hb = (__hip_bfloat16*)alloc((size_t)NN * 128 * 2);
    __hip_bfloat16* Cb = (__hip_bfloat16*)alloc((size_t)NN * 1536 * 2);  // 6 tables; layer1 [N,128]x6, layer2 [N,256]x6
    __hip_bfloat16* T1 = (__hip_bfloat16*)alloc((size_t)768 * 128 * 2);
    __hip_bfloat16* T2 = (__hip_bfloat16*)alloc((size_t)1536 * 128 * 2);
    int* deg  = (int*)alloc((size_t)TN * 4);
    int* offs = (int*)alloc((size_t)TN * 4);
    int* curs = (int*)alloc((size_t)TN * 4);
    int* esrc = (int*)alloc((size_t)RR * EE * 4);
    int* part = (int*)alloc(4096);

    float* outp = (float*)d_out;

    // conversions / weight packing
    conv_bf16_kernel<<<25000, 256, 0, stream>>>(x, xb, NN * 128);
    transpose_w_kernel<<<192, 256, 0, stream>>>(W1s, T1, 128, 0);
    transpose_w_kernel<<<192, 256, 0, stream>>>(W1d, T1, 128, 128);
    transpose_w_kernel<<<384, 256, 0, stream>>>(W2s, T2, 256, 0);
    transpose_w_kernel<<<384, 256, 0, stream>>>(W2d, T2, 256, 256);

    // CSR build (shared by both layers)
    hipMemsetAsync(deg, 0, (size_t)TN * 4, stream);
    hist_kernel<<<(RR * EE) / 256, 256, 0, stream>>>(dst, deg);
    scan1_kernel<<<NCHUNK, 256, 0, stream>>>(deg, part);
    scan2_kernel<<<1, 1, 0, stream>>>(part);
    scan3_kernel<<<NCHUNK, 256, 0, stream>>>(deg, part, offs, curs);
    scatter_kernel<<<(RR * EE) / 256, 256, 0, stream>>>(src, dst, curs, esrc);

    // Layer 1: GEMM [N,128]x[128,768] -> 6 compact [N,128] tables; agg fuses relu+bf16 -> hb
    gemm_kernel<<<dim3(782, 12), 256, 0, stream>>>(xb, T1, Cb, NN, 7);
    agg_kernel<2, true><<<12500, 256, 0, stream>>>((const ushort*)Cb, a1, offs, deg, esrc,
                                                   nullptr, hb);

    // Layer 2: GEMM [N,128]x[128,1536] -> 6 compact [N,256] tables; agg -> f32 d_out
    gemm_kernel<<<dim3(782, 24), 256, 0, stream>>>(hb, T2, Cb, NN, 8);
    agg_kernel<4, false><<<12500, 256, 0, stream>>>((const ushort*)Cb, a2, offs, deg, esrc,
                                                    outp, nullptr);
}